// Round 1
// baseline (479.603 us; speedup 1.0000x reference)
//
#include <hip/hip_runtime.h>
#include <math.h>

// ---------------------------------------------------------------------------
// PAPE Transformer encoder layer, MI355X/gfx950.
// Pipeline: f32->bf16 casts, fused QKV GEMM (N=3072), V transpose,
// flash-attention w/ additive bias, Wo GEMM + residual, LN1,
// FFN1 GEMM + exact GELU, FFN2 GEMM + residual, LN2 -> d_out (f32).
// All GEMMs are X[M,K] @ W[N,K]^T  (B^T layout, k-major both operands).
// ---------------------------------------------------------------------------

using bf16_t = __bf16;
using bf16x8 = __attribute__((ext_vector_type(8))) __bf16;
using bf16x4 = __attribute__((ext_vector_type(4))) __bf16;
using f32x4  = __attribute__((ext_vector_type(4))) float;

#define DEV_INLINE __device__ __forceinline__

DEV_INLINE void lds_load16(const void* g, void* l) {
  // async global->LDS, 16B per lane. LDS dest = wave-uniform base + lane*16.
  __builtin_amdgcn_global_load_lds(
      (__attribute__((address_space(1))) void*)(g),
      (__attribute__((address_space(3))) void*)(l), 16, 0, 0);
}

// ---------------------------------------------------------------------------
// f32 -> bf16 elementwise cast (n % 4 == 0)
// ---------------------------------------------------------------------------
__global__ __launch_bounds__(256)
void f32_to_bf16_k(const float* __restrict__ in, bf16_t* __restrict__ out, int n) {
  int i = (blockIdx.x * 256 + threadIdx.x) * 4;
  if (i >= n) return;
  float4 v = *(const float4*)(in + i);
  bf16x4 o = {(bf16_t)v.x, (bf16_t)v.y, (bf16_t)v.z, (bf16_t)v.w};
  *(bf16x4*)(out + i) = o;
}

__global__ __launch_bounds__(256)
void copy_f32_k(const float* __restrict__ in, float* __restrict__ out, int n) {
  int i = blockIdx.x * 256 + threadIdx.x;
  if (i < n) out[i] = in[i];
}

// ---------------------------------------------------------------------------
// GEMM: out[M,N] = A[M,K] @ Bw[N,K]^T + bias  (+ epilogue)
// 128x128 tile, BK=32, 4 waves (2x2), each wave 64x64 via 4x4 16x16x32 MFMAs.
// MODE 0: bf16 out;  MODE 1: exact-GELU -> bf16 out;  MODE 2: +resid -> f32 out
// ---------------------------------------------------------------------------
template <int MODE>
__global__ __launch_bounds__(256)
void gemm_bt(const bf16_t* __restrict__ A, const bf16_t* __restrict__ Bw,
             const float* __restrict__ bias, const float* __restrict__ resid,
             void* __restrict__ outp, int M, int N, int K) {
  __shared__ bf16_t sA[128 * 32];
  __shared__ bf16_t sB[128 * 32];

  const int tid  = threadIdx.x;
  const int lane = tid & 63, wid = tid >> 6;
  const int wr = wid >> 1, wc = wid & 1;
  const int brow = blockIdx.y, bcol = blockIdx.x;
  const int lm = lane & 15, lk = lane >> 4;

  f32x4 zero = {0.f, 0.f, 0.f, 0.f};
  f32x4 acc[4][4];
#pragma unroll
  for (int i = 0; i < 4; ++i)
#pragma unroll
    for (int j = 0; j < 4; ++j) acc[i][j] = zero;

  // staging: issue t in {0,1}: LDS byte = t*4096 + tid*16 -> row t*64+wid*16+lane/4
  const int srow = wid * 16 + (lane >> 2);
  const int scol = (lane & 3) * 8;
  const bf16_t* Abase = A  + (size_t)(brow * 128 + srow) * K + scol;
  const bf16_t* Bbase = Bw + (size_t)(bcol * 128 + srow) * K + scol;
  char* sAw = (char*)sA + wid * 1024;
  char* sBw = (char*)sB + wid * 1024;

  for (int kk = 0; kk < K; kk += 32) {
    lds_load16(Abase + kk,                   sAw);
    lds_load16(Abase + (size_t)64 * K + kk,  sAw + 4096);
    lds_load16(Bbase + kk,                   sBw);
    lds_load16(Bbase + (size_t)64 * K + kk,  sBw + 4096);
    __syncthreads();  // drains vmcnt -> staged data visible

    bf16x8 a[4], b[4];
#pragma unroll
    for (int mi = 0; mi < 4; ++mi)
      a[mi] = *(const bf16x8*)(sA + (wr * 64 + mi * 16 + lm) * 32 + lk * 8);
#pragma unroll
    for (int ni = 0; ni < 4; ++ni)
      b[ni] = *(const bf16x8*)(sB + (wc * 64 + ni * 16 + lm) * 32 + lk * 8);
#pragma unroll
    for (int mi = 0; mi < 4; ++mi)
#pragma unroll
      for (int ni = 0; ni < 4; ++ni)
        acc[mi][ni] = __builtin_amdgcn_mfma_f32_16x16x32_bf16(a[mi], b[ni], acc[mi][ni], 0, 0, 0);
    __syncthreads();  // compute done before next stage overwrites
  }

  // epilogue: C/D layout: row=(lane>>4)*4+j, col=lane&15 (verified m89/m91)
#pragma unroll
  for (int mi = 0; mi < 4; ++mi) {
#pragma unroll
    for (int ni = 0; ni < 4; ++ni) {
#pragma unroll
      for (int j = 0; j < 4; ++j) {
        int row = brow * 128 + wr * 64 + mi * 16 + lk * 4 + j;
        int col = bcol * 128 + wc * 64 + ni * 16 + lm;
        float v = acc[mi][ni][j] + bias[col];
        if (MODE == 1) v = 0.5f * v * (1.f + erff(v * 0.70710678118f));
        if (MODE == 2) {
          ((float*)outp)[(size_t)row * N + col] = v + resid[(size_t)row * N + col];
        } else {
          ((bf16_t*)outp)[(size_t)row * N + col] = (bf16_t)v;
        }
      }
    }
  }
}

// ---------------------------------------------------------------------------
// V transpose: qkv[b, s, 2048 + h*64 + d] -> vt[(b*16+h)*64 + d, s]
// 64x64 tiles through padded LDS.
// ---------------------------------------------------------------------------
__global__ __launch_bounds__(256)
void transpose_v(const bf16_t* __restrict__ qkv, bf16_t* __restrict__ vt) {
  __shared__ bf16_t tile[64][65];
  const int bid = blockIdx.x;           // (b<<9) | (h<<5) | st
  const int st = bid & 31, h = (bid >> 5) & 15, b = bid >> 9;
  const int tid = threadIdx.x;
  const int r = tid >> 3, c0 = (tid & 7) * 8;
#pragma unroll
  for (int p = 0; p < 2; ++p) {
    int rr = p * 32 + r;
    const bf16_t* g = qkv + (size_t)(b * 2048 + st * 64 + rr) * 3072 + 2048 + h * 64 + c0;
    bf16x8 v = *(const bf16x8*)g;
#pragma unroll
    for (int i = 0; i < 8; ++i) tile[rr][c0 + i] = v[i];
  }
  __syncthreads();
#pragma unroll
  for (int p = 0; p < 2; ++p) {
    int d = p * 32 + r;
    bf16x8 o;
#pragma unroll
    for (int i = 0; i < 8; ++i) o[i] = tile[c0 + i][d];
    *(bf16x8*)(vt + ((size_t)(b * 16 + h) * 64 + d) * 2048 + st * 64 + c0) = o;
  }
}

// ---------------------------------------------------------------------------
// Flash attention with additive relative bias.
// Block = 4 waves, Q-tile 64 rows (wave w owns rows w*16..w*16+15), KV-tile 64.
// scores = Q K^T / 8 + bias[h]; online softmax (fp32); P -> LDS bf16 -> PV MFMA.
// b is the LOW bit of blockIdx so both batches hit the same bias tile in L2/L3.
// ---------------------------------------------------------------------------
__global__ __launch_bounds__(256)
void attn_k(const bf16_t* __restrict__ qkv, const bf16_t* __restrict__ vt,
            const float* __restrict__ bias, bf16_t* __restrict__ outp) {
  __shared__ bf16_t Qs[64 * 64];
  __shared__ bf16_t Ks[64 * 64];
  __shared__ bf16_t Vs[64 * 64];
  __shared__ bf16_t Ps[4][16 * 64];

  const int bid = blockIdx.x;           // (h<<6) | (qt<<1) | b
  const int b  = bid & 1;
  const int qt = (bid >> 1) & 31;
  const int h  = bid >> 6;

  const int tid = threadIdx.x;
  const int lane = tid & 63, wid = tid >> 6;
  const int lm = lane & 15, lk = lane >> 4;

  const int srow = tid >> 3;            // 0..31
  const int sd   = (tid & 7) * 8;

  // stage Q tile (once)
  {
    const bf16_t* qg = qkv + (size_t)(b * 2048 + qt * 64 + srow) * 3072 + h * 64 + sd;
    lds_load16(qg,                      (char*)Qs + wid * 1024);
    lds_load16(qg + (size_t)32 * 3072,  (char*)Qs + 4096 + wid * 1024);
  }
  __syncthreads();

  bf16x8 qa[2];
#pragma unroll
  for (int ks = 0; ks < 2; ++ks)
    qa[ks] = *(const bf16x8*)(Qs + (wid * 16 + lm) * 64 + ks * 32 + lk * 8);

  f32x4 zero = {0.f, 0.f, 0.f, 0.f};
  f32x4 acc_o[4];
  float m_run[4], l_run[4];
#pragma unroll
  for (int j = 0; j < 4; ++j) { acc_o[j] = zero; m_run[j] = -1e30f; l_run[j] = 0.f; }

  const bf16_t* kg0 = qkv + 1024 + (size_t)(b * 2048 + srow) * 3072 + h * 64 + sd;
  const bf16_t* vg0 = vt + ((size_t)((b * 16 + h) * 64) + srow) * 2048 + sd;
  const float* bias0 = bias + ((size_t)h * 2048 + qt * 64 + wid * 16 + lk * 4) * 2048 + lm;

  for (int kt = 0; kt < 32; ++kt) {
    __syncthreads();  // prev compute done before overwrite
    lds_load16(kg0 + (size_t)(kt * 64) * 3072,        (char*)Ks + wid * 1024);
    lds_load16(kg0 + (size_t)(kt * 64 + 32) * 3072,   (char*)Ks + 4096 + wid * 1024);
    lds_load16(vg0 + kt * 64,                          (char*)Vs + wid * 1024);
    lds_load16(vg0 + (size_t)32 * 2048 + kt * 64,      (char*)Vs + 4096 + wid * 1024);
    __syncthreads();  // staged data visible

    // bias loads first (hide latency under MFMAs)
    const float* bp = bias0 + (size_t)kt * 64;
    float bb[4][4];
#pragma unroll
    for (int ni = 0; ni < 4; ++ni)
#pragma unroll
      for (int j = 0; j < 4; ++j)
        bb[ni][j] = bp[(size_t)j * 2048 + ni * 16];

    // QK^T
    f32x4 sc[4];
#pragma unroll
    for (int ni = 0; ni < 4; ++ni) sc[ni] = zero;
#pragma unroll
    for (int ks = 0; ks < 2; ++ks) {
#pragma unroll
      for (int ni = 0; ni < 4; ++ni) {
        bf16x8 kb = *(const bf16x8*)(Ks + (ni * 16 + lm) * 64 + ks * 32 + lk * 8);
        sc[ni] = __builtin_amdgcn_mfma_f32_16x16x32_bf16(qa[ks], kb, sc[ni], 0, 0, 0);
      }
    }

    float s[4][4], p_[4][4];
#pragma unroll
    for (int ni = 0; ni < 4; ++ni)
#pragma unroll
      for (int j = 0; j < 4; ++j)
        s[ni][j] = sc[ni][j] * 0.125f + bb[ni][j];

    // row-max over 64 cols: 4 local + 16-lane butterfly (rows live in 16-lane groups)
    float mloc[4], rs[4], scl[4];
#pragma unroll
    for (int j = 0; j < 4; ++j)
      mloc[j] = fmaxf(fmaxf(s[0][j], s[1][j]), fmaxf(s[2][j], s[3][j]));
#pragma unroll
    for (int off = 1; off < 16; off <<= 1)
#pragma unroll
      for (int j = 0; j < 4; ++j)
        mloc[j] = fmaxf(mloc[j], __shfl_xor(mloc[j], off, 64));

#pragma unroll
    for (int j = 0; j < 4; ++j) {
      float mnew = fmaxf(m_run[j], mloc[j]);
      scl[j] = __expf(m_run[j] - mnew);
      m_run[j] = mnew;
      rs[j] = 0.f;
#pragma unroll
      for (int ni = 0; ni < 4; ++ni) { p_[ni][j] = __expf(s[ni][j] - mnew); rs[j] += p_[ni][j]; }
    }
#pragma unroll
    for (int off = 1; off < 16; off <<= 1)
#pragma unroll
      for (int j = 0; j < 4; ++j)
        rs[j] += __shfl_xor(rs[j], off, 64);
#pragma unroll
    for (int j = 0; j < 4; ++j) l_run[j] = l_run[j] * scl[j] + rs[j];
#pragma unroll
    for (int nf = 0; nf < 4; ++nf)
#pragma unroll
      for (int j = 0; j < 4; ++j) acc_o[nf][j] *= scl[j];

    // P -> LDS (own wave region; same-wave RAW, compiler orders lgkmcnt)
    bf16_t* pw = &Ps[wid][0];
#pragma unroll
    for (int ni = 0; ni < 4; ++ni)
#pragma unroll
      for (int j = 0; j < 4; ++j)
        pw[(lk * 4 + j) * 64 + ni * 16 + lm] = (bf16_t)p_[ni][j];

    // PV: A = P[16 x 64], B = Vt rows (d) k-major in kv
#pragma unroll
    for (int ks = 0; ks < 2; ++ks) {
      bf16x8 pa = *(const bf16x8*)(pw + lm * 64 + ks * 32 + lk * 8);
#pragma unroll
      for (int nf = 0; nf < 4; ++nf) {
        bf16x8 vb = *(const bf16x8*)(Vs + (nf * 16 + lm) * 64 + ks * 32 + lk * 8);
        acc_o[nf] = __builtin_amdgcn_mfma_f32_16x16x32_bf16(pa, vb, acc_o[nf], 0, 0, 0);
      }
    }
  }

  // epilogue: out[b*2048 + q, h*64 + d] bf16
#pragma unroll
  for (int nf = 0; nf < 4; ++nf) {
#pragma unroll
    for (int j = 0; j < 4; ++j) {
      float o = acc_o[nf][j] / l_run[j];
      outp[(size_t)(b * 2048 + qt * 64 + wid * 16 + lk * 4 + j) * 1024 + h * 64 + nf * 16 + lm] = (bf16_t)o;
    }
  }
}

// ---------------------------------------------------------------------------
// LayerNorm over last dim (1024). One row per block. Optional bf16 copy out.
// ---------------------------------------------------------------------------
__global__ __launch_bounds__(256)
void layernorm_k(const float* __restrict__ in, const float* __restrict__ gamma,
                 const float* __restrict__ beta, float* __restrict__ out32,
                 bf16_t* __restrict__ out16) {
  const int row = blockIdx.x, tid = threadIdx.x;
  const int lane = tid & 63, wid = tid >> 6;
  const float4 v = ((const float4*)(in + (size_t)row * 1024))[tid];
  float s  = v.x + v.y + v.z + v.w;
  float s2 = v.x * v.x + v.y * v.y + v.z * v.z + v.w * v.w;
#pragma unroll
  for (int off = 32; off; off >>= 1) {
    s  += __shfl_xor(s, off, 64);
    s2 += __shfl_xor(s2, off, 64);
  }
  __shared__ float red[8];
  if (lane == 0) { red[wid] = s; red[wid + 4] = s2; }
  __syncthreads();
  s  = red[0] + red[1] + red[2] + red[3];
  s2 = red[4] + red[5] + red[6] + red[7];
  const float mu  = s * (1.f / 1024.f);
  const float inv = rsqrtf(s2 * (1.f / 1024.f) - mu * mu + 1e-5f);
  const float4 g4 = ((const float4*)gamma)[tid];
  const float4 b4 = ((const float4*)beta)[tid];
  float4 o;
  o.x = (v.x - mu) * inv * g4.x + b4.x;
  o.y = (v.y - mu) * inv * g4.y + b4.y;
  o.z = (v.z - mu) * inv * g4.z + b4.z;
  o.w = (v.w - mu) * inv * g4.w + b4.w;
  ((float4*)(out32 + (size_t)row * 1024))[tid] = o;
  if (out16) {
    bf16x4 ob = {(bf16_t)o.x, (bf16_t)o.y, (bf16_t)o.z, (bf16_t)o.w};
    *(bf16x4*)(out16 + (size_t)row * 1024 + tid * 4) = ob;
  }
}

// ---------------------------------------------------------------------------
extern "C" void kernel_launch(void* const* d_in, const int* in_sizes, int n_in,
                              void* d_out, int out_size, void* d_ws, size_t ws_size,
                              hipStream_t stream) {
  const float* src  = (const float*)d_in[0];
  const float* rbias= (const float*)d_in[1];
  const float* Wq   = (const float*)d_in[2];
  const float* bq   = (const float*)d_in[3];
  const float* Wk   = (const float*)d_in[4];
  const float* bk   = (const float*)d_in[5];
  const float* Wv   = (const float*)d_in[6];
  const float* bv   = (const float*)d_in[7];
  const float* Wo   = (const float*)d_in[8];
  const float* bo   = (const float*)d_in[9];
  const float* W1   = (const float*)d_in[10];
  const float* b1   = (const float*)d_in[11];
  const float* W2   = (const float*)d_in[12];
  const float* b2   = (const float*)d_in[13];
  const float* g1   = (const float*)d_in[14];
  const float* be1  = (const float*)d_in[15];
  const float* g2   = (const float*)d_in[16];
  const float* be2  = (const float*)d_in[17];

  char* ws = (char*)d_ws;
  const size_t MB = 1u << 20;
  bf16_t* src_bf  = (bf16_t*)(ws + 0);        //  8 MB [4096,1024]
  bf16_t* wqkv_bf = (bf16_t*)(ws + 8 * MB);   //  6 MB [3072,1024]
  bf16_t* wo_bf   = (bf16_t*)(ws + 14 * MB);  //  2 MB
  bf16_t* w1_bf   = (bf16_t*)(ws + 16 * MB);  //  8 MB [4096,1024]
  bf16_t* w2_bf   = (bf16_t*)(ws + 24 * MB);  //  8 MB [1024,4096]
  float*  bqkv    = (float*)(ws + 32 * MB);   // 12 KB
  bf16_t* qkv_bf  = (bf16_t*)(ws + 33 * MB);  // 24 MB [4096,3072]
  bf16_t* vt      = (bf16_t*)(ws + 57 * MB);  //  8 MB [32*64,2048]
  bf16_t* attn_bf = (bf16_t*)(ws + 65 * MB);  //  8 MB [4096,1024]
  float*  y1      = (float*)(ws + 73 * MB);   // 16 MB
  float*  xf      = (float*)(ws + 89 * MB);   // 16 MB
  bf16_t* x_bf    = (bf16_t*)(ws + 105 * MB); //  8 MB
  bf16_t* h_bf    = (bf16_t*)(ws + 113 * MB); // 32 MB [4096,4096]
  float*  y2      = (float*)(ws + 145 * MB);  // 16 MB  (total 161 MB)

  auto cvt = [&](const float* s, bf16_t* d, int n) {
    f32_to_bf16_k<<<n / 1024, 256, 0, stream>>>(s, d, n);
  };
  cvt(src, src_bf, 4096 * 1024);
  cvt(Wq, wqkv_bf,               1024 * 1024);
  cvt(Wk, wqkv_bf + 1024 * 1024, 1024 * 1024);
  cvt(Wv, wqkv_bf + 2 * 1024 * 1024, 1024 * 1024);
  cvt(Wo, wo_bf, 1024 * 1024);
  cvt(W1, w1_bf, 4096 * 1024);
  cvt(W2, w2_bf, 4096 * 1024);
  copy_f32_k<<<4, 256, 0, stream>>>(bq, bqkv, 1024);
  copy_f32_k<<<4, 256, 0, stream>>>(bk, bqkv + 1024, 1024);
  copy_f32_k<<<4, 256, 0, stream>>>(bv, bqkv + 2048, 1024);

  // fused QKV projection: [4096,3072]
  gemm_bt<0><<<dim3(3072 / 128, 4096 / 128), 256, 0, stream>>>(
      src_bf, wqkv_bf, bqkv, nullptr, qkv_bf, 4096, 3072, 1024);
  transpose_v<<<1024, 256, 0, stream>>>(qkv_bf, vt);
  attn_k<<<1024, 256, 0, stream>>>(qkv_bf, vt, rbias, attn_bf);
  // output projection + residual(src)
  gemm_bt<2><<<dim3(1024 / 128, 4096 / 128), 256, 0, stream>>>(
      attn_bf, wo_bf, bo, src, y1, 4096, 1024, 1024);
  layernorm_k<<<4096, 256, 0, stream>>>(y1, g1, be1, xf, x_bf);
  // FFN1 + exact GELU
  gemm_bt<1><<<dim3(4096 / 128, 4096 / 128), 256, 0, stream>>>(
      x_bf, w1_bf, b1, nullptr, h_bf, 4096, 4096, 1024);
  // FFN2 + residual(x)
  gemm_bt<2><<<dim3(1024 / 128, 4096 / 128), 256, 0, stream>>>(
      h_bf, w2_bf, b2, xf, y2, 4096, 1024, 4096);
  layernorm_k<<<4096, 256, 0, stream>>>(y2, g2, be2, (float*)d_out, nullptr);
}

// Round 3
// 432.263 us; speedup vs baseline: 1.1095x; 1.1095x over previous
//
#include <hip/hip_runtime.h>
#include <math.h>

// ---------------------------------------------------------------------------
// PAPE Transformer encoder layer, MI355X/gfx950.  Round 3 (= R2 + compile fix):
//  - attn: LDS XOR-swizzle (kills 16-way bank conflicts), 2-phase double-
//    buffered K/V staging (1 barrier/tile), setprio around MFMA, Q staged
//    into the P buffer (LDS 40KB -> 4 blocks/CU).
//  - Wo & FFN2 (N=1024): split-K=2 in one launch (grid.z=2) -> f32 partials;
//    LayerNorm fused to consume partialA+partialB+bias+residual.
//  - fix: no arrays of LDS-derived pointers (gfx950 static-initializer error);
//    double-buffer selected via byte offset at use site.
// ---------------------------------------------------------------------------

using bf16_t = __bf16;
using bf16x8 = __attribute__((ext_vector_type(8))) __bf16;
using bf16x4 = __attribute__((ext_vector_type(4))) __bf16;
using f32x4  = __attribute__((ext_vector_type(4))) float;

#define DEV_INLINE __device__ __forceinline__

DEV_INLINE void lds_load16(const void* g, void* l) {
  __builtin_amdgcn_global_load_lds(
      (__attribute__((address_space(1))) void*)(g),
      (__attribute__((address_space(3))) void*)(l), 16, 0, 0);
}

// swizzled 8x bf16 read from a [rows][64] bf16 tile (128B rows):
// element chunk c of row r lives at byte r*128 + ((c ^ (r&7))<<4)
DEV_INLINE bf16x8 lds_read8_sw(const bf16_t* base, int row, int chunk) {
  return *(const bf16x8*)((const char*)base + row * 128 + (((chunk) ^ (row & 7)) << 4));
}

// ---------------------------------------------------------------------------
__global__ __launch_bounds__(256)
void f32_to_bf16_k(const float* __restrict__ in, bf16_t* __restrict__ out, int n) {
  int i = (blockIdx.x * 256 + threadIdx.x) * 4;
  if (i >= n) return;
  float4 v = *(const float4*)(in + i);
  bf16x4 o = {(bf16_t)v.x, (bf16_t)v.y, (bf16_t)v.z, (bf16_t)v.w};
  *(bf16x4*)(out + i) = o;
}

__global__ __launch_bounds__(256)
void copy_f32_k(const float* __restrict__ in, float* __restrict__ out, int n) {
  int i = blockIdx.x * 256 + threadIdx.x;
  if (i < n) out[i] = in[i];
}

// ---------------------------------------------------------------------------
// GEMM: out[M,N] = A[M,K] @ Bw[N,K]^T (+ bias / epilogue)
// 128x128 tile, BK=32, 4 waves (2x2), wave 64x64 via 4x4 16x16x32 MFMAs.
// MODE 0: +bias -> bf16 out
// MODE 1: +bias, exact GELU -> bf16 out
// MODE 3: raw f32 partial out (split-K via blockIdx.z; out += z*M*N, A/B += z*K)
// ---------------------------------------------------------------------------
template <int MODE>
__global__ __launch_bounds__(256)
void gemm_bt(const bf16_t* __restrict__ A, int lda,
             const bf16_t* __restrict__ Bw, int ldb,
             const float* __restrict__ bias,
             void* __restrict__ outp, int M, int N, int K) {
  __shared__ bf16_t sA[128 * 32];
  __shared__ bf16_t sB[128 * 32];

  const int tid  = threadIdx.x;
  const int lane = tid & 63, wid = tid >> 6;
  const int wr = wid >> 1, wc = wid & 1;
  const int brow = blockIdx.y, bcol = blockIdx.x;
  const int lm = lane & 15, lk = lane >> 4;
  const int z = blockIdx.z;

  A  += (size_t)z * K;   // split-K column offset (z==0 for MODE 0/1)
  Bw += (size_t)z * K;

  f32x4 zero = {0.f, 0.f, 0.f, 0.f};
  f32x4 acc[4][4];
#pragma unroll
  for (int i = 0; i < 4; ++i)
#pragma unroll
    for (int j = 0; j < 4; ++j) acc[i][j] = zero;

  const int srow = wid * 16 + (lane >> 2);
  const int scol = (lane & 3) * 8;
  const bf16_t* Abase = A  + (size_t)(brow * 128 + srow) * lda + scol;
  const bf16_t* Bbase = Bw + (size_t)(bcol * 128 + srow) * ldb + scol;
  char* sAw = (char*)sA + wid * 1024;
  char* sBw = (char*)sB + wid * 1024;

  for (int kk = 0; kk < K; kk += 32) {
    lds_load16(Abase + kk,                    sAw);
    lds_load16(Abase + (size_t)64 * lda + kk, sAw + 4096);
    lds_load16(Bbase + kk,                    sBw);
    lds_load16(Bbase + (size_t)64 * ldb + kk, sBw + 4096);
    __syncthreads();

    bf16x8 a[4], b[4];
#pragma unroll
    for (int mi = 0; mi < 4; ++mi)
      a[mi] = *(const bf16x8*)(sA + (wr * 64 + mi * 16 + lm) * 32 + lk * 8);
#pragma unroll
    for (int ni = 0; ni < 4; ++ni)
      b[ni] = *(const bf16x8*)(sB + (wc * 64 + ni * 16 + lm) * 32 + lk * 8);
    __builtin_amdgcn_s_setprio(1);
#pragma unroll
    for (int mi = 0; mi < 4; ++mi)
#pragma unroll
      for (int ni = 0; ni < 4; ++ni)
        acc[mi][ni] = __builtin_amdgcn_mfma_f32_16x16x32_bf16(a[mi], b[ni], acc[mi][ni], 0, 0, 0);
    __builtin_amdgcn_s_setprio(0);
    __syncthreads();
  }

#pragma unroll
  for (int mi = 0; mi < 4; ++mi) {
#pragma unroll
    for (int ni = 0; ni < 4; ++ni) {
#pragma unroll
      for (int j = 0; j < 4; ++j) {
        int row = brow * 128 + wr * 64 + mi * 16 + lk * 4 + j;
        int col = bcol * 128 + wc * 64 + ni * 16 + lm;
        if (MODE == 3) {
          ((float*)outp)[(size_t)z * M * N + (size_t)row * N + col] = acc[mi][ni][j];
        } else {
          float v = acc[mi][ni][j] + bias[col];
          if (MODE == 1) v = 0.5f * v * (1.f + erff(v * 0.70710678118f));
          ((bf16_t*)outp)[(size_t)row * N + col] = (bf16_t)v;
        }
      }
    }
  }
}

// ---------------------------------------------------------------------------
// V transpose: qkv[b, s, 2048 + h*64 + d] -> vt[(b*16+h)*64 + d, s]
// ---------------------------------------------------------------------------
__global__ __launch_bounds__(256)
void transpose_v(const bf16_t* __restrict__ qkv, bf16_t* __restrict__ vt) {
  __shared__ bf16_t tile[64][65];
  const int bid = blockIdx.x;
  const int st = bid & 31, h = (bid >> 5) & 15, b = bid >> 9;
  const int tid = threadIdx.x;
  const int r = tid >> 3, c0 = (tid & 7) * 8;
#pragma unroll
  for (int p = 0; p < 2; ++p) {
    int rr = p * 32 + r;
    const bf16_t* g = qkv + (size_t)(b * 2048 + st * 64 + rr) * 3072 + 2048 + h * 64 + c0;
    bf16x8 v = *(const bf16x8*)g;
#pragma unroll
    for (int i = 0; i < 8; ++i) tile[rr][c0 + i] = v[i];
  }
  __syncthreads();
#pragma unroll
  for (int p = 0; p < 2; ++p) {
    int d = p * 32 + r;
    bf16x8 o;
#pragma unroll
    for (int i = 0; i < 8; ++i) o[i] = tile[c0 + i][d];
    *(bf16x8*)(vt + ((size_t)(b * 16 + h) * 64 + d) * 2048 + st * 64 + c0) = o;
  }
}

// ---------------------------------------------------------------------------
// Flash attention with additive relative bias.
// 4 waves; wave w owns q-rows w*16..w*16+15 of a 64-row Q tile; KV tile 64.
// LDS: Ks[2],Vs[2] double-buffered + Ps (Q staged here first). All tiles
// XOR-swizzled (chunk ^= row&7) -> conflict-free ds_read_b128.
// 2-phase: stage(kt+1) issued before compute(kt); one barrier per tile.
// ---------------------------------------------------------------------------
__global__ __launch_bounds__(256)
void attn_k(const bf16_t* __restrict__ qkv, const bf16_t* __restrict__ vt,
            const float* __restrict__ bias, bf16_t* __restrict__ outp) {
  __shared__ bf16_t Ks[2][64 * 64];
  __shared__ bf16_t Vs[2][64 * 64];
  __shared__ bf16_t Ps[64 * 64];   // Q tile at start, then P per wave region

  const int bid = blockIdx.x;           // (h<<6) | (qt<<1) | b
  const int b  = bid & 1;
  const int qt = (bid >> 1) & 31;
  const int h  = bid >> 6;

  const int tid = threadIdx.x;
  const int lane = tid & 63, wid = tid >> 6;
  const int lm = lane & 15, lk = lane >> 4;

  const int srow = tid >> 3;                        // 0..31
  const int sd   = (((tid & 7) ^ (srow & 7)) * 8);  // swizzle-adjusted col

  const bf16_t* qg  = qkv + (size_t)(b * 2048 + qt * 64 + srow) * 3072 + h * 64 + sd;
  const bf16_t* kg0 = qkv + 1024 + (size_t)(b * 2048 + srow) * 3072 + h * 64 + sd;
  const bf16_t* vg0 = vt + ((size_t)((b * 16 + h) * 64) + srow) * 2048 + sd;

  auto stageKV = [&](int kt, int buf) {
    char* kb = (char*)Ks + buf * 8192;
    char* vb = (char*)Vs + buf * 8192;
    lds_load16(kg0 + (size_t)(kt * 64) * 3072,      kb + wid * 1024);
    lds_load16(kg0 + (size_t)(kt * 64 + 32) * 3072, kb + 4096 + wid * 1024);
    lds_load16(vg0 + kt * 64,                       vb + wid * 1024);
    lds_load16(vg0 + (size_t)32 * 2048 + kt * 64,   vb + 4096 + wid * 1024);
  };

  // prologue: stage Q (into Ps) + tile 0
  lds_load16(qg,                     (char*)Ps + wid * 1024);
  lds_load16(qg + (size_t)32 * 3072, (char*)Ps + 4096 + wid * 1024);
  stageKV(0, 0);
  __syncthreads();

  bf16x8 qa[2];
#pragma unroll
  for (int ks = 0; ks < 2; ++ks)
    qa[ks] = lds_read8_sw(Ps, wid * 16 + lm, ks * 4 + lk);  // own wave's rows only

  f32x4 zero = {0.f, 0.f, 0.f, 0.f};
  f32x4 acc_o[4];
  float m_run[4], l_run[4];
#pragma unroll
  for (int j = 0; j < 4; ++j) { acc_o[j] = zero; m_run[j] = -1e30f; l_run[j] = 0.f; }

  bf16_t* PsW = Ps + wid * 16 * 64;
  const float* bias0 = bias + ((size_t)h * 2048 + qt * 64 + wid * 16 + lk * 4) * 2048 + lm;

  for (int kt = 0; kt < 32; ++kt) {
    const int cur = kt & 1;
    if (kt < 31) stageKV(kt + 1, cur ^ 1);   // prefetch: drains at end-of-iter barrier

    // bias tile -> registers (overlaps with MFMA)
    const float* bp = bias0 + (size_t)kt * 64;
    float bb[4][4];
#pragma unroll
    for (int ni = 0; ni < 4; ++ni)
#pragma unroll
      for (int j = 0; j < 4; ++j)
        bb[ni][j] = bp[(size_t)j * 2048 + ni * 16];

    // QK^T
    const bf16_t* Kcur = (const bf16_t*)((const char*)Ks + cur * 8192);
    const bf16_t* Vcur = (const bf16_t*)((const char*)Vs + cur * 8192);
    f32x4 sc[4];
#pragma unroll
    for (int ni = 0; ni < 4; ++ni) sc[ni] = zero;
    __builtin_amdgcn_s_setprio(1);
#pragma unroll
    for (int ks = 0; ks < 2; ++ks) {
#pragma unroll
      for (int ni = 0; ni < 4; ++ni) {
        bf16x8 kb = lds_read8_sw(Kcur, ni * 16 + lm, ks * 4 + lk);
        sc[ni] = __builtin_amdgcn_mfma_f32_16x16x32_bf16(qa[ks], kb, sc[ni], 0, 0, 0);
      }
    }
    __builtin_amdgcn_s_setprio(0);

    float s[4][4], p_[4][4];
#pragma unroll
    for (int ni = 0; ni < 4; ++ni)
#pragma unroll
      for (int j = 0; j < 4; ++j)
        s[ni][j] = sc[ni][j] * 0.125f + bb[ni][j];

    float mloc[4], rs[4], scl[4];
#pragma unroll
    for (int j = 0; j < 4; ++j)
      mloc[j] = fmaxf(fmaxf(s[0][j], s[1][j]), fmaxf(s[2][j], s[3][j]));
#pragma unroll
    for (int off = 1; off < 16; off <<= 1)
#pragma unroll
      for (int j = 0; j < 4; ++j)
        mloc[j] = fmaxf(mloc[j], __shfl_xor(mloc[j], off, 64));

#pragma unroll
    for (int j = 0; j < 4; ++j) {
      float mnew = fmaxf(m_run[j], mloc[j]);
      scl[j] = __expf(m_run[j] - mnew);
      m_run[j] = mnew;
      rs[j] = 0.f;
#pragma unroll
      for (int ni = 0; ni < 4; ++ni) { p_[ni][j] = __expf(s[ni][j] - mnew); rs[j] += p_[ni][j]; }
    }
#pragma unroll
    for (int off = 1; off < 16; off <<= 1)
#pragma unroll
      for (int j = 0; j < 4; ++j)
        rs[j] += __shfl_xor(rs[j], off, 64);
#pragma unroll
    for (int j = 0; j < 4; ++j) l_run[j] = l_run[j] * scl[j] + rs[j];
#pragma unroll
    for (int nf = 0; nf < 4; ++nf)
#pragma unroll
      for (int j = 0; j < 4; ++j) acc_o[nf][j] *= scl[j];

    // P -> LDS (own wave region, swizzled; element (r, ni*16+lm))
#pragma unroll
    for (int ni = 0; ni < 4; ++ni)
#pragma unroll
      for (int j = 0; j < 4; ++j) {
        int r = lk * 4 + j;
        *(bf16_t*)((char*)PsW + r * 128 + (((ni * 2 + (lm >> 3)) ^ (r & 7)) << 4) + (lm & 7) * 2)
            = (bf16_t)p_[ni][j];
      }

    // PV
#pragma unroll
    for (int ks = 0; ks < 2; ++ks) {
      bf16x8 pa = lds_read8_sw(PsW, lm, ks * 4 + lk);
      __builtin_amdgcn_s_setprio(1);
#pragma unroll
      for (int nf = 0; nf < 4; ++nf) {
        bf16x8 vb = lds_read8_sw(Vcur, nf * 16 + lm, ks * 4 + lk);
        acc_o[nf] = __builtin_amdgcn_mfma_f32_16x16x32_bf16(pa, vb, acc_o[nf], 0, 0, 0);
      }
      __builtin_amdgcn_s_setprio(0);
    }

    __syncthreads();   // drains prefetch vmcnt + syncs buffers
  }

#pragma unroll
  for (int nf = 0; nf < 4; ++nf) {
#pragma unroll
    for (int j = 0; j < 4; ++j) {
      float o = acc_o[nf][j] / l_run[j];
      outp[(size_t)(b * 2048 + qt * 64 + wid * 16 + lk * 4 + j) * 1024 + h * 64 + nf * 16 + lm] = (bf16_t)o;
    }
  }
}

// ---------------------------------------------------------------------------
// Fused LayerNorm over last dim (1024):
//   in = pa + pb + bias[col] + resid   (split-K partial sums + bias + residual)
// One row per block. Optional bf16 copy out.
// ---------------------------------------------------------------------------
__global__ __launch_bounds__(256)
void layernorm2_k(const float* __restrict__ pa, const float* __restrict__ pb,
                  const float* __restrict__ bias, const float* __restrict__ resid,
                  const float* __restrict__ gamma, const float* __restrict__ beta,
                  float* __restrict__ out32, bf16_t* __restrict__ out16) {
  const int row = blockIdx.x, tid = threadIdx.x;
  const int lane = tid & 63, wid = tid >> 6;
  const size_t base = (size_t)row * 1024;
  float4 v  = ((const float4*)(pa + base))[tid];
  float4 v2 = ((const float4*)(pb + base))[tid];
  float4 bb = ((const float4*)bias)[tid];
  float4 rr = ((const float4*)(resid + base))[tid];
  v.x += v2.x + bb.x + rr.x;
  v.y += v2.y + bb.y + rr.y;
  v.z += v2.z + bb.z + rr.z;
  v.w += v2.w + bb.w + rr.w;
  float s  = v.x + v.y + v.z + v.w;
  float s2 = v.x * v.x + v.y * v.y + v.z * v.z + v.w * v.w;
#pragma unroll
  for (int off = 32; off; off >>= 1) {
    s  += __shfl_xor(s, off, 64);
    s2 += __shfl_xor(s2, off, 64);
  }
  __shared__ float red[8];
  if (lane == 0) { red[wid] = s; red[wid + 4] = s2; }
  __syncthreads();
  s  = red[0] + red[1] + red[2] + red[3];
  s2 = red[4] + red[5] + red[6] + red[7];
  const float mu  = s * (1.f / 1024.f);
  const float inv = rsqrtf(s2 * (1.f / 1024.f) - mu * mu + 1e-5f);
  const float4 g4 = ((const float4*)gamma)[tid];
  const float4 b4 = ((const float4*)beta)[tid];
  float4 o;
  o.x = (v.x - mu) * inv * g4.x + b4.x;
  o.y = (v.y - mu) * inv * g4.y + b4.y;
  o.z = (v.z - mu) * inv * g4.z + b4.z;
  o.w = (v.w - mu) * inv * g4.w + b4.w;
  ((float4*)(out32 + base))[tid] = o;
  if (out16) {
    bf16x4 ob = {(bf16_t)o.x, (bf16_t)o.y, (bf16_t)o.z, (bf16_t)o.w};
    *(bf16x4*)(out16 + base + tid * 4) = ob;
  }
}

// ---------------------------------------------------------------------------
extern "C" void kernel_launch(void* const* d_in, const int* in_sizes, int n_in,
                              void* d_out, int out_size, void* d_ws, size_t ws_size,
                              hipStream_t stream) {
  const float* src  = (const float*)d_in[0];
  const float* rbias= (const float*)d_in[1];
  const float* Wq   = (const float*)d_in[2];
  const float* bq   = (const float*)d_in[3];
  const float* Wk   = (const float*)d_in[4];
  const float* bk   = (const float*)d_in[5];
  const float* Wv   = (const float*)d_in[6];
  const float* bv   = (const float*)d_in[7];
  const float* Wo   = (const float*)d_in[8];
  const float* bo   = (const float*)d_in[9];
  const float* W1   = (const float*)d_in[10];
  const float* b1   = (const float*)d_in[11];
  const float* W2   = (const float*)d_in[12];
  const float* b2   = (const float*)d_in[13];
  const float* g1   = (const float*)d_in[14];
  const float* be1  = (const float*)d_in[15];
  const float* g2   = (const float*)d_in[16];
  const float* be2  = (const float*)d_in[17];

  char* ws = (char*)d_ws;
  const size_t MB = 1u << 20;
  bf16_t* src_bf  = (bf16_t*)(ws + 0);        //  8 MB [4096,1024]
  bf16_t* wqkv_bf = (bf16_t*)(ws + 8 * MB);   //  6 MB [3072,1024]
  bf16_t* wo_bf   = (bf16_t*)(ws + 14 * MB);  //  2 MB
  bf16_t* w1_bf   = (bf16_t*)(ws + 16 * MB);  //  8 MB [4096,1024]
  bf16_t* w2_bf   = (bf16_t*)(ws + 24 * MB);  //  8 MB [1024,4096]
  float*  bqkv    = (float*)(ws + 32 * MB);   // 12 KB
  bf16_t* qkv_bf  = (bf16_t*)(ws + 33 * MB);  // 24 MB [4096,3072]
  bf16_t* vt      = (bf16_t*)(ws + 57 * MB);  //  8 MB [32*64,2048]
  bf16_t* attn_bf = (bf16_t*)(ws + 65 * MB);  //  8 MB [4096,1024]
  float*  pA      = (float*)(ws + 73 * MB);   // 16 MB split-K partial 0
  float*  pB      = (float*)(ws + 89 * MB);   // 16 MB split-K partial 1
  float*  xf      = (float*)(ws + 105 * MB);  // 16 MB
  bf16_t* x_bf    = (bf16_t*)(ws + 121 * MB); //  8 MB
  bf16_t* h_bf    = (bf16_t*)(ws + 129 * MB); // 32 MB [4096,4096]  (total 161)

  auto cvt = [&](const float* s, bf16_t* d, int n) {
    f32_to_bf16_k<<<n / 1024, 256, 0, stream>>>(s, d, n);
  };
  cvt(src, src_bf, 4096 * 1024);
  cvt(Wq, wqkv_bf,                   1024 * 1024);
  cvt(Wk, wqkv_bf + 1024 * 1024,     1024 * 1024);
  cvt(Wv, wqkv_bf + 2 * 1024 * 1024, 1024 * 1024);
  cvt(Wo, wo_bf, 1024 * 1024);
  cvt(W1, w1_bf, 4096 * 1024);
  cvt(W2, w2_bf, 4096 * 1024);
  copy_f32_k<<<4, 256, 0, stream>>>(bq, bqkv, 1024);
  copy_f32_k<<<4, 256, 0, stream>>>(bk, bqkv + 1024, 1024);
  copy_f32_k<<<4, 256, 0, stream>>>(bv, bqkv + 2048, 1024);

  // fused QKV projection: [4096,3072]
  gemm_bt<0><<<dim3(24, 32), 256, 0, stream>>>(
      src_bf, 1024, wqkv_bf, 1024, bqkv, qkv_bf, 4096, 3072, 1024);
  transpose_v<<<1024, 256, 0, stream>>>(qkv_bf, vt);
  attn_k<<<1024, 256, 0, stream>>>(qkv_bf, vt, rbias, attn_bf);

  // output projection, split-K=2 -> partials; LN1 fuses +bo+src
  gemm_bt<3><<<dim3(8, 32, 2), 256, 0, stream>>>(
      attn_bf, 1024, wo_bf, 1024, nullptr, pA, 4096, 1024, 512);
  layernorm2_k<<<4096, 256, 0, stream>>>(pA, pB, bo, src, g1, be1, xf, x_bf);

  // FFN1 + exact GELU
  gemm_bt<1><<<dim3(32, 32), 256, 0, stream>>>(
      x_bf, 1024, w1_bf, 1024, b1, h_bf, 4096, 4096, 1024);

  // FFN2, split-K=2 -> partials; LN2 fuses +b2+xf
  gemm_bt<3><<<dim3(8, 32, 2), 256, 0, stream>>>(
      h_bf, 4096, w2_bf, 4096, nullptr, pA, 4096, 1024, 2048);
  layernorm2_k<<<4096, 256, 0, stream>>>(pA, pB, b2, xf, g2, be2, (float*)d_out, nullptr);
}